// Round 20
// baseline (158.385 us; speedup 1.0000x reference)
//
#include <hip/hip_runtime.h>

// Problem constants
constexpr int BN_  = 16;                 // batch
constexpr int SN_  = 577;                // seq
constexpr int SP_  = 640;                // padded seq (multiple of 64)
constexpr int DN_  = 768;                // model dim
constexpr int HN_  = 12;                 // heads
constexpr int HD_  = 64;                 // head dim
constexpr int NB_  = 50;                 // rpe buckets
constexpr int MR_  = BN_ * SN_;          // 9232 rows of x
constexpr int MRP_ = 73 * 128;           // 9344 padded rows
constexpr int NQ_  = 3 * DN_;            // 2304 qkv cols
constexpr int BHS_ = BN_ * HN_ * SN_;    // 110784 (b,h,i) rows
constexpr int SHD_ = SN_ * HD_;          // 36928

constexpr int NBX_ = MRP_ * DN_ / 2048;  // 3504 blocks for x cvt
constexpr int NBW_ = NQ_ * DN_ / 2048;   // 864 blocks for w cvt
constexpr int NRPX_ = 5 * 4 * 2 * 10 * 4 * 64;   // 102400 dwords in rpbX
constexpr int NBRX_ = NRPX_ / 256;               // 400 blocks for rpbX

constexpr int QKV_WG_ = 18 * 73;         // 1314 qkv workgroups

typedef __attribute__((ext_vector_type(8))) short short8;
typedef __attribute__((ext_vector_type(4))) float f32x4;

__device__ __forceinline__ short f2bf(float f) {
  union { float f; unsigned u; } v; v.f = f;
  unsigned r = (v.u + 0x7fffu + ((v.u >> 16) & 1u)) >> 16;
  return (short)r;
}

// raw v_exp_f32: D = 2^S0 (handles -3e38 -> 0)
__device__ __forceinline__ float ex2(float x) {
  float r; asm("v_exp_f32 %0, %1" : "=v"(r) : "v"(x)); return r;
}

// v_cvt_pk_bf16_f32: dst = {lo16=bf16(a), hi16=bf16(b)}
__device__ __forceinline__ unsigned cvtpk(float a, float b) {
  unsigned r; asm("v_cvt_pk_bf16_f32 %0, %1, %2" : "=v"(r) : "v"(a), "v"(b));
  return r;
}

__device__ __forceinline__ float bf2f(unsigned short u) {
  union { unsigned u; float f; } v; v.u = ((unsigned)u) << 16; return v.f;
}

// async global->LDS, 16B per lane; LDS dest is wave-uniform base + lane*16
__device__ __forceinline__ void gload16(const void* g, void* l) {
  __builtin_amdgcn_global_load_lds(
      (const __attribute__((address_space(1))) unsigned int*)g,
      (__attribute__((address_space(3))) unsigned int*)l, 16, 0, 0);
}

// ---------------------------------------------------------------------------
// Kernel 0 (fused prep): x->bf16 (padded), w->bf16, rp_bucket->rpbX.
// ---------------------------------------------------------------------------
__launch_bounds__(256)
__global__ void prep_k(const float* __restrict__ x, short* __restrict__ xb,
                       const float* __restrict__ w, short* __restrict__ wb,
                       const int* __restrict__ rpb, unsigned* __restrict__ rpbX) {
  const int bid = blockIdx.x;
  const int t = threadIdx.x;
  if (bid < NBX_ + NBW_) {
    const float* src; short* dst; int n_src, i;
    if (bid < NBX_) { src = x; dst = xb; n_src = MR_ * DN_; i = (bid * 256 + t) * 8; }
    else { src = w; dst = wb; n_src = NQ_ * DN_; i = ((bid - NBX_) * 256 + t) * 8; }
    union { short8 v; short u[8]; } pk;
    if (i < n_src) {
      const float4 a = *(const float4*)(src + i);
      const float4 b = *(const float4*)(src + i + 4);
      pk.u[0] = f2bf(a.x); pk.u[1] = f2bf(a.y); pk.u[2] = f2bf(a.z); pk.u[3] = f2bf(a.w);
      pk.u[4] = f2bf(b.x); pk.u[5] = f2bf(b.y); pk.u[6] = f2bf(b.z); pk.u[7] = f2bf(b.w);
    } else {
#pragma unroll
      for (int j = 0; j < 8; ++j) pk.u[j] = 0;
    }
    *(short8*)(dst + i) = pk.v;
  } else {
    const int idx = (bid - NBX_ - NBW_) * 256 + t;   // dword index
    if (idx >= NRPX_) return;
    const int lane = idx & 63, chunk = idx >> 6;
    const int nt = chunk & 3;
    const int jt = (chunk >> 2) % 10;
    const int rest = chunk / 40;
    const int s  = rest & 1;
    const int w4 = (rest >> 1) & 3;
    const int qt = rest >> 3;
    const int g = lane >> 4, ln = lane & 15;
    int row = qt * 128 + w4 * 32 + s * 16 + ln;
    if (row > SN_ - 1) row = SN_ - 1;
    const int j0 = jt * 64 + nt * 16 + 4 * g;
    union { unsigned u; uchar4 c; } pk;
    pk.c.x = (j0     < SN_) ? (unsigned char)rpb[row * SN_ + j0    ] : 0;
    pk.c.y = (j0 + 1 < SN_) ? (unsigned char)rpb[row * SN_ + j0 + 1] : 0;
    pk.c.z = (j0 + 2 < SN_) ? (unsigned char)rpb[row * SN_ + j0 + 2] : 0;
    pk.c.w = (j0 + 3 < SN_) ? (unsigned char)rpb[row * SN_ + j0 + 3] : 0;
    rpbX[idx] = pk.u;
  }
}

// ---------------------------------------------------------------------------
// Kernel 1: qkv = x @ w^T in bf16 MFMA (unchanged R15: T4 2-deep counted
// vmcnt pipeline, pre-swizzled gload source, LDS-staged coalesced epilogue,
// bijective XCD swizzle).
// ---------------------------------------------------------------------------
__launch_bounds__(256)
__global__ void qkv_mfma_k(const short* __restrict__ xb, const short* __restrict__ wb,
                           short* __restrict__ Qbf, short* __restrict__ Ksw,
                           short* __restrict__ Vbf) {
  __shared__ short SB[32768];   // 64 KB: A buf0|A buf1|B buf0|B buf1; epilogue reuse
  const int t = threadIdx.x;
  const int w = t >> 6, lane = t & 63, g = lane >> 4, ln = lane & 15;
  const int wm = w >> 1, wn = w & 1;

  // bijective XCD swizzle: nwg=1314, 8 XCDs: q=164, r=2
  const int bid = blockIdx.x;
  const int xcd = bid & 7, li = bid >> 3;
  const int sid = (xcd < 2) ? xcd * 165 + li : 2 * 165 + (xcd - 2) * 164 + li;
  const int mi = sid / 18, ni = sid - mi * 18;
  const int m0 = mi * 128, n0 = ni * 128;

  const int rlo = lane >> 3;
  const int gu  = (lane & 7) ^ rlo;
  const short* ga[4]; const short* gb[4];
  int lOff[4];
#pragma unroll
  for (int q = 0; q < 4; ++q) {
    const int rl = w * 32 + q * 8 + rlo;
    ga[q] = xb + (size_t)(m0 + rl) * DN_ + gu * 8;
    gb[q] = wb + (size_t)(n0 + rl) * DN_ + gu * 8;
    lOff[q] = w * 2048 + q * 512;     // wave-uniform (shorts)
  }

  f32x4 acc[4][4];
#pragma unroll
  for (int mt = 0; mt < 4; ++mt)
#pragma unroll
    for (int nt = 0; nt < 4; ++nt) acc[mt][nt] = (f32x4){0.f, 0.f, 0.f, 0.f};

  // prologue: tile 0 -> buf0, tile 1 -> buf1 (16 loads in flight)
#pragma unroll
  for (int q = 0; q < 4; ++q) {
    gload16(ga[q], SB + lOff[q]);
    gload16(gb[q], SB + 16384 + lOff[q]);
  }
#pragma unroll
  for (int q = 0; q < 4; ++q) {
    gload16(ga[q] + 64, SB + 8192 + lOff[q]);
    gload16(gb[q] + 64, SB + 16384 + 8192 + lOff[q]);
  }

  int cur = 0;
  for (int k0 = 0; k0 < DN_; k0 += 64) {
    if (k0 + 64 < DN_) {
      asm volatile("s_waitcnt vmcnt(8)" ::: "memory");
    } else {
      asm volatile("s_waitcnt vmcnt(0)" ::: "memory");
    }
    __builtin_amdgcn_sched_barrier(0);
    __builtin_amdgcn_s_barrier();   // all waves' tile-k data visible
    __builtin_amdgcn_sched_barrier(0);

    const short* Ac = SB + cur * 8192;
    const short* Bc = SB + 16384 + cur * 8192;
#pragma unroll
    for (int kc = 0; kc < 2; ++kc) {
      short8 af[4], bf[4];
#pragma unroll
      for (int mt = 0; mt < 4; ++mt) {
        const int row = wm * 64 + mt * 16 + ln;
        const int u = (kc * 4 + g) ^ (row & 7);
        af[mt] = *(const short8*)&Ac[row * 64 + u * 8];
      }
#pragma unroll
      for (int nt = 0; nt < 4; ++nt) {
        const int row = wn * 64 + nt * 16 + ln;
        const int u = (kc * 4 + g) ^ (row & 7);
        bf[nt] = *(const short8*)&Bc[row * 64 + u * 8];
      }
#pragma unroll
      for (int mt = 0; mt < 4; ++mt)
#pragma unroll
        for (int nt = 0; nt < 4; ++nt)
          acc[mt][nt] = __builtin_amdgcn_mfma_f32_16x16x32_bf16(af[mt], bf[nt], acc[mt][nt], 0, 0, 0);
    }

    __builtin_amdgcn_s_barrier();   // all reads of buf[cur] done
    __builtin_amdgcn_sched_barrier(0);

    if (k0 + 128 < DN_) {  // issue tile k+2 into the just-read buffer
      const int nb = cur * 8192;
#pragma unroll
      for (int q = 0; q < 4; ++q) {
        gload16(ga[q] + k0 + 128, SB + nb + lOff[q]);
        gload16(gb[q] + k0 + 128, SB + 16384 + nb + lOff[q]);
      }
    }
    cur ^= 1;
  }

  // ---- epilogue: stage C tile (bf16) through LDS, coalesced 16B stores ----
  const int wbase = w * 4608;               // 64 rows x stride 72 per wave
  const int nw0  = n0 + wn * 64;
  const int secg = nw0 / DN_;               // uniform per wave
  const int cbw  = nw0 - secg * DN_;
  const float QSC = 0.18033688011112042f;   // log2(e) / 8
#pragma unroll
  for (int mt = 0; mt < 4; ++mt)
#pragma unroll
    for (int nt = 0; nt < 4; ++nt)
#pragma unroll
      for (int r = 0; r < 4; ++r) {
        float v = acc[mt][nt][r];
        if (secg == 0) v *= QSC;
        SB[wbase + (mt * 16 + 4 * g + r) * 72 + nt * 16 + ln] = f2bf(v);
      }
  const int gm = m0 + wm * 64 + lane;
  if (gm < MR_) {
    const int bb = gm / SN_;
    const int ss = gm - bb * SN_;
    const int pr = ss * DN_ + cbw;          // multiple of 64
    const int hh = pr / SHD_;
    const int ii = (pr - hh * SHD_) >> 6;
    const size_t ro = (size_t)(bb * HN_ + hh);
    const short* src = SB + wbase + lane * 72;
    if (secg == 0) {
      short* dst = Qbf + (ro * SN_ + ii) * 64;
#pragma unroll
      for (int u = 0; u < 8; ++u)
        *(short8*)(dst + u * 8) = *(const short8*)(src + u * 8);
    } else if (secg == 1) {
      short* dst = Ksw + (ro * SP_ + ii) * 64;
      const int sw = ii & 7;
#pragma unroll
      for (int u = 0; u < 8; ++u)
        *(short8*)(dst + (u ^ sw) * 8) = *(const short8*)(src + u * 8);
    } else {
      short* dst = Vbf + (ro * SP_ + ii) * 64;
#pragma unroll
      for (int u = 0; u < 8; ++u)
        *(short8*)(dst + u * 8) = *(const short8*)(src + u * 8);
    }
  }
}

// ---------------------------------------------------------------------------
// Kernel 2: transpose V per (bh): Vbf[j][d] -> Vtsw[d][pi(j)], bf16 (as R15).
// ---------------------------------------------------------------------------
__launch_bounds__(256)
__global__ void vtr_k(const short* __restrict__ Vbf, short* __restrict__ Vtsw) {
  __shared__ short T[64][72];
  const int t = threadIdx.x;
  const int jt = blockIdx.x, bh = blockIdx.y;
  const int j0 = jt * 64;
  {
    const int r = t >> 2, c0 = (t & 3) * 16;
    const short* src = Vbf + ((size_t)bh * SP_ + j0 + r) * 64 + c0;
    *(short8*)&T[r][c0]     = *(const short8*)(src);
    *(short8*)&T[r][c0 + 8] = *(const short8*)(src + 8);
  }
  __syncthreads();
  const int d = t >> 2;
  short* dst = Vtsw + ((size_t)bh * 64 + d) * SP_;
  const int sw = (d & 7) << 3;
#pragma unroll
  for (int e = 0; e < 4; ++e) {
    const int jl = (t & 3) * 16 + e * 4;
    const int jg = j0 + jl;
    short4 v;
    v.x = (jg + 0 < SN_) ? T[jl + 0][d] : (short)0;
    v.y = (jg + 1 < SN_) ? T[jl + 1][d] : (short)0;
    v.z = (jg + 2 < SN_) ? T[jl + 2][d] : (short)0;
    v.w = (jg + 3 < SN_) ? T[jl + 3][d] : (short)0;
    const int oq = (jg >> 2) & 7;
    const int pq = ((oq & 3) << 1) | (oq >> 2);
    const int p  = (jg & ~31) | (pq << 2);
    *(short4*)&dst[p ^ sw] = v;
  }
}

// ---------------------------------------------------------------------------
// Kernel 3: MFMA flash attention, SPLIT-K over j: 2 blocks per (bh,qt), each
// covering 5 of 10 j-tiles with the identical proven R15 inner loop; writes
// bf16 partial O + (m,l) per half. Grid 1920 -> 7.5 blocks/CU (2x TLP).
// cmb_k merges. Partials overlay dead xb/wb/Vbf ws regions.
// ---------------------------------------------------------------------------
__launch_bounds__(256)
__global__ void attn_k(const short* __restrict__ Qbf, const short* __restrict__ Ksw,
                       const short* __restrict__ Vtsw, const float* __restrict__ rpe,
                       const unsigned* __restrict__ rpbX,
                       short* __restrict__ Oa, short* __restrict__ Ob,
                       float* __restrict__ ml) {
  __shared__ short Kt[4096];                  // 8 KB
  __shared__ short Vt[4096];                  // 8 KB
  __shared__ unsigned short ctxs[4][32][53];  // 13.25 KB bf16; Rp overlays it
  short (*Rp)[64] = (short (*)[64])ctxs;      // [64][64] bf16, prologue only

  const int t = threadIdx.x;
  const int w = t >> 6, lane = t & 63, g = lane >> 4, ln = lane & 15;
  // XCD swizzle: all 10 (qt,half) slots of one bh share an XCD
  const int wg = blockIdx.x;
  const int xcd = wg & 7, idx = wg >> 3;
  const int sub = idx % 10;
  const int qt = sub % 5, half = sub / 5;
  const int bh = (idx / 10) * 8 + xcd;
  const int i0 = qt * 128;
  const int jt0 = half * 5;
  const size_t rb = (size_t)bh * SN_;
  const short* Kbh = Ksw + (size_t)bh * SP_ * 64;
  const short* Vbh = Vtsw + (size_t)bh * 64 * SP_;

  // staging maps
  const int tK = t * 8;                          // K/V: linear, 2x 16B
  const int vRow = t >> 3, vCol = (t & 7) * 8;   // V global rows

  // coalesced bucket-table base
  const unsigned* rpB = rpbX + qt * 20480 + w * 5120 + lane;

  // issue first-tile K/V loads (tile jt0)
  short8 kr0, kr1, vr0, vr1;
  kr0 = *(const short8*)(Kbh + (size_t)(jt0 * 64) * 64 + tK);
  kr1 = *(const short8*)(Kbh + (size_t)(jt0 * 64) * 64 + 2048 + tK);
  vr0 = *(const short8*)(Vbh + (size_t)vRow * SP_ + jt0 * 64 + vCol);
  vr1 = *(const short8*)(Vbh + (size_t)(32 + vRow) * SP_ + jt0 * 64 + vCol);

  // stage rpe^T -> Rp[c][d] (bf16), pad c>=50 with 0   (overlays ctxs)
  for (int e = t; e < 64 * 64; e += 256) {
    const int c = e >> 6, d = e & 63;
    Rp[c][d] = (c < NB_) ? f2bf(rpe[d * NB_ + c]) : (short)0;
  }

  // Q fragments, 2 sets: set s covers rows i0 + 32w + 16s + ln
  short8 qf[2][2];
#pragma unroll
  for (int s = 0; s < 2; ++s) {
    int row = i0 + 32 * w + 16 * s + ln; if (row > SN_ - 1) row = SN_ - 1;
    const short* qp = Qbf + (rb + row) * 64;
    qf[s][0] = *(const short8*)(qp + 8 * g);
    qf[s][1] = *(const short8*)(qp + 32 + 8 * g);
  }

  __syncthreads();  // B1: Rp visible

  // ctx tiles (both sets) into registers
  f32x4 accC[2][4];
#pragma unroll
  for (int s = 0; s < 2; ++s)
#pragma unroll
    for (int ct = 0; ct < 4; ++ct) accC[s][ct] = (f32x4){0.f, 0.f, 0.f, 0.f};
#pragma unroll
  for (int kc = 0; kc < 2; ++kc) {
#pragma unroll
    for (int ct = 0; ct < 4; ++ct) {
      const short8 rf = *(const short8*)&Rp[ct * 16 + ln][kc * 32 + 8 * g];
      accC[0][ct] = __builtin_amdgcn_mfma_f32_16x16x32_bf16(qf[0][kc], rf, accC[0][ct], 0, 0, 0);
      accC[1][ct] = __builtin_amdgcn_mfma_f32_16x16x32_bf16(qf[1][kc], rf, accC[1][ct], 0, 0, 0);
    }
  }
  __syncthreads();  // B2: ALL waves' Rp reads done -> ctxs overlay safe

  // write ctxs (bf16); wave-local region, read only by this wave
#pragma unroll
  for (int s = 0; s < 2; ++s)
#pragma unroll
    for (int ct = 0; ct < 4; ++ct) {
      const int c = ct * 16 + ln;
      if (c < 53) {
#pragma unroll
        for (int r = 0; r < 4; ++r)
          ctxs[w][16 * s + 4 * g + r][c] = (unsigned short)f2bf(accC[s][ct][r]);
      }
    }

  float m0s = -3e38f, m1s = -3e38f, l0s = 0.f, l1s = 0.f;
  f32x4 accO[2][4];
#pragma unroll
  for (int s = 0; s < 2; ++s)
#pragma unroll
    for (int dt = 0; dt < 4; ++dt) accO[s][dt] = (f32x4){0.f, 0.f, 0.f, 0.f};

  const int swv = (ln & 7) << 3;

  for (int jt = jt0; jt < jt0 + 5; ++jt) {
    __syncthreads();  // B_a: previous compute's LDS reads done
    *(short8*)&Kt[tK]        = kr0;
    *(short8*)&Kt[2048 + tK] = kr1;
    *(short8*)&Vt[tK]        = vr0;
    *(short8*)&Vt[2048 + tK] = vr1;
    __syncthreads();  // B_b: tiles visible

    // bucket loads for THIS tile: 8 wave-coalesced dwords (L2-resident)
    unsigned rpg[2][4];
#pragma unroll
    for (int s = 0; s < 2; ++s)
#pragma unroll
      for (int nt = 0; nt < 4; ++nt)
        rpg[s][nt] = rpB[s * 2560 + jt * 256 + nt * 64];

    if (jt < jt0 + 4) {  // prefetch next K/V tile of this half
      const int jn = jt * 64 + 64;
      kr0 = *(const short8*)(Kbh + (size_t)jn * 64 + tK);
      kr1 = *(const short8*)(Kbh + (size_t)jn * 64 + 2048 + tK);
      vr0 = *(const short8*)(Vbh + (size_t)vRow * SP_ + jn + vCol);
      vr1 = *(const short8*)(Vbh + (size_t)(32 + vRow) * SP_ + jn + vCol);
    }

    // QK^T both sets (K frags shared): accS[s][nt][r] = S_s[i=ln][j=nt*16+4g+r]
    f32x4 accS[2][4];
#pragma unroll
    for (int s = 0; s < 2; ++s)
#pragma unroll
      for (int nt = 0; nt < 4; ++nt) accS[s][nt] = (f32x4){0.f, 0.f, 0.f, 0.f};
    __builtin_amdgcn_s_setprio(1);
#pragma unroll
    for (int kc = 0; kc < 2; ++kc) {
      const int cb = (kc * 32 + 8 * g) ^ swv;
#pragma unroll
      for (int nt = 0; nt < 4; ++nt) {
        const short8 kf = *(const short8*)&Kt[(nt * 16 + ln) * 64 + cb];
        accS[0][nt] = __builtin_amdgcn_mfma_f32_16x16x32_bf16(kf, qf[0][kc], accS[0][nt], 0, 0, 0);
        accS[1][nt] = __builtin_amdgcn_mfma_f32_16x16x32_bf16(kf, qf[1][kc], accS[1][nt], 0, 0, 0);
      }
    }
    __builtin_amdgcn_s_setprio(0);

    // per set: bias + softmax + pack
    short8 pf[2][2];
#pragma unroll
    for (int s = 0; s < 2; ++s) {
      const unsigned short* cbase = &ctxs[w][16 * s + ln][0];
      float pv[4][4];
#pragma unroll
      for (int nt = 0; nt < 4; ++nt) {
        union { unsigned u; uchar4 c; } bk; bk.u = rpg[s][nt];
        pv[nt][0] = accS[s][nt][0] + bf2f(cbase[bk.c.x]);
        pv[nt][1] = accS[s][nt][1] + bf2f(cbase[bk.c.y]);
        pv[nt][2] = accS[s][nt][2] + bf2f(cbase[bk.c.z]);
        pv[nt][3] = accS[s][nt][3] + bf2f(cbase[bk.c.w]);
      }
      if (jt == 9) {  // tail: REPLACE invalid-j entries (poison-proof)
#pragma unroll
        for (int nt = 0; nt < 4; ++nt) {
          const int jb = jt * 64 + nt * 16 + 4 * g;
#pragma unroll
          for (int r = 0; r < 4; ++r)
            if (jb + r >= SN_) pv[nt][r] = -3e38f;
        }
      }

      float& m = (s == 0) ? m0s : m1s;
      float& l = (s == 0) ? l0s : l1s;

      float mq[4];
#pragma unroll
      for (int nt = 0; nt < 4; ++nt)
        mq[nt] = fmaxf(fmaxf(pv[nt][0], pv[nt][1]), fmaxf(pv[nt][2], pv[nt][3]));
      float mx = fmaxf(fmaxf(mq[0], mq[1]), fmaxf(mq[2], mq[3]));
      mx = fmaxf(mx, __shfl_xor(mx, 16));
      mx = fmaxf(mx, __shfl_xor(mx, 32));

      if (__any(mx > m + 8.f)) {
        const float mnew = fmaxf(m, mx);
        const float sc = ex2(m - mnew);
        float scr[4];
#pragma unroll
        for (int r = 0; r < 4; ++r) scr[r] = __shfl(sc, 4 * g + r);
#pragma unroll
        for (int dt = 0; dt < 4; ++dt)
#pragma unroll
          for (int r = 0; r < 4; ++r) accO[s][dt][r] *= scr[r];
        l *= sc;
        m = mnew;
      }

#pragma unroll
      for (int nt = 0; nt < 4; ++nt)
#pragma unroll
        for (int r = 0; r < 4; ++r)
          pv[nt][r] = ex2(pv[nt][r] - m);
      float sq[4];
#pragma unroll
      for (int nt = 0; nt < 4; ++nt)
        sq[nt] = (pv[nt][0] + pv[nt][1]) + (pv[nt][2] + pv[nt][3]);
      float sum = (sq[0] + sq[1]) + (sq[2] + sq[3]);
      sum += __shfl_xor(sum, 16);
      sum += __shfl_xor(sum, 32);
      l += sum;

#pragma unroll
      for (int kc = 0; kc < 2; ++kc) {
        union { short8 v; unsigned wd[4]; } pk;
        pk.wd[0] = cvtpk(pv[2 * kc][0],     pv[2 * kc][1]);
        pk.wd[1] = cvtpk(pv[2 * kc][2],     pv[2 * kc][3]);
        pk.wd[2] = cvtpk(pv[2 * kc + 1][0], pv[2 * kc + 1][1]);
        pk.wd[3] = cvtpk(pv[2 * kc + 1][2], pv[2 * kc + 1][3]);
        pf[s][kc] = pk.v;
      }
    }

    // PV both sets (V frags shared, single b128 each thanks to permuted V)
    __builtin_amdgcn_s_setprio(1);
#pragma unroll
    for (int kc = 0; kc < 2; ++kc) {
      const int cb = (kc * 32 + 8 * g) ^ swv;
#pragma unroll
      for (int dt = 0; dt < 4; ++dt) {
        const short8 vf = *(const short8*)&Vt[(dt * 16 + ln) * 64 + cb];
        accO[0][dt] = __builtin_amdgcn_mfma_f32_16x16x32_bf16(pf[0][kc], vf, accO[0][dt], 0, 0, 0);
        accO[1][dt] = __builtin_amdgcn_mfma_f32_16x16x32_bf16(pf[1][kc], vf, accO[1][dt], 0, 0, 0);
      }
    }
    __builtin_amdgcn_s_setprio(0);
  }

  // epilogue: write bf16 partial O and per-row (m, l) for this half
  float* mArr = ml + (size_t)half * 2 * BHS_;
  float* lArr = mArr + BHS_;
  short* Oh = half ? Ob : Oa;
#pragma unroll
  for (int s = 0; s < 2; ++s) {
    const float mv = (s == 0) ? m0s : m1s;
    const float lv = (s == 0) ? l0s : l1s;
    const int ri = i0 + 32 * w + 16 * s + ln;
    if (g == 0 && ri < SN_) {   // m,l replicated across g-groups for same ln
      mArr[rb + ri] = mv;
      lArr[rb + ri] = lv;
    }
#pragma unroll
    for (int r = 0; r < 4; ++r) {
      const int i = i0 + 32 * w + 16 * s + 4 * g + r;
      if (i >= SN_) continue;
      short* op = Oh + (rb + i) * 64 + ln;
#pragma unroll
      for (int dt = 0; dt < 4; ++dt) op[dt * 16] = f2bf(accO[s][dt][r]);
    }
  }
}

// ---------------------------------------------------------------------------
// Kernel 4: combine the two split-K halves:
// y = (Oa*ex2(ma-M) + Ob*ex2(mb-M)) / (la*ex2(ma-M) + lb*ex2(mb-M)), M=max.
// 8 threads per row, each handles 8 contiguous d (32B y store).
// ---------------------------------------------------------------------------
__launch_bounds__(256)
__global__ void cmb_k(const short* __restrict__ Oa, const short* __restrict__ Ob,
                      const float* __restrict__ ml, float* __restrict__ y) {
  const int gtid = blockIdx.x * 256 + threadIdx.x;
  const int row = gtid >> 3;
  if (row >= BHS_) return;
  const int dseg = (gtid & 7) * 8;
  const float ma_ = ml[row],            la_ = ml[BHS_ + row];
  const float mb_ = ml[2 * BHS_ + row], lb_ = ml[3 * BHS_ + row];
  const float M  = fmaxf(ma_, mb_);
  const float ea = ex2(ma_ - M), eb = ex2(mb_ - M);
  const float inv = 1.f / (la_ * ea + lb_ * eb);
  const float fa = ea * inv, fb = eb * inv;
  union { short8 v; short u[8]; } oa, ob;
  oa.v = *(const short8*)(Oa + (size_t)row * 64 + dseg);
  ob.v = *(const short8*)(Ob + (size_t)row * 64 + dseg);
  const int bh = row / SN_;
  const int i  = row - bh * SN_;
  const int b  = bh / HN_;
  const int h  = bh - b * HN_;
  float* yp = y + ((size_t)b * SN_ + i) * DN_ + h * HD_ + dseg;
  float4 o0, o1;
  o0.x = bf2f((unsigned short)oa.u[0]) * fa + bf2f((unsigned short)ob.u[0]) * fb;
  o0.y = bf2f((unsigned short)oa.u[1]) * fa + bf2f((unsigned short)ob.u[1]) * fb;
  o0.z = bf2f((unsigned short)oa.u[2]) * fa + bf2f((unsigned short)ob.u[2]) * fb;
  o0.w = bf2f((unsigned short)oa.u[3]) * fa + bf2f((unsigned short)ob.u[3]) * fb;
  o1.x = bf2f((unsigned short)oa.u[4]) * fa + bf2f((unsigned short)ob.u[4]) * fb;
  o1.y = bf2f((unsigned short)oa.u[5]) * fa + bf2f((unsigned short)ob.u[5]) * fb;
  o1.z = bf2f((unsigned short)oa.u[6]) * fa + bf2f((unsigned short)ob.u[6]) * fb;
  o1.w = bf2f((unsigned short)oa.u[7]) * fa + bf2f((unsigned short)ob.u[7]) * fb;
  *(float4*)yp       = o0;
  *(float4*)(yp + 4) = o1;
}

// ---------------------------------------------------------------------------
extern "C" void kernel_launch(void* const* d_in, const int* in_sizes, int n_in,
                              void* d_out, int out_size, void* d_ws, size_t ws_size,
                              hipStream_t stream) {
  const float* x   = (const float*)d_in[0];
  const float* w   = (const float*)d_in[1];
  const float* rpe = (const float*)d_in[2];
  const int*   rpb = (const int*)d_in[3];
  float* y = (float*)d_out;

  short* xb   = (short*)d_ws;                      // 9344*768 (dead after qkv)
  short* wb   = xb + (size_t)MRP_ * DN_;           // 2304*768 (dead after qkv)
  short* Qbf  = wb + (size_t)NQ_ * DN_;            // 110784*64
  short* Ksw  = Qbf + (size_t)BHS_ * HD_;          // 192*640*64
  short* Vbf  = Ksw + (size_t)BN_ * HN_ * SP_ * 64;  // dead after vtr
  short* Vtsw = Vbf + (size_t)BN_ * HN_ * SP_ * 64;
  unsigned* rpbX = (unsigned*)(Vtsw + (size_t)BN_ * HN_ * 64 * SP_);  // 400 KB

  // split-K partials overlay dead regions (attn/cmb run after qkv/vtr):
  short* Oa  = xb;             // BHS*64 bf16 = 14.2 MB < xb 14.35 MB
  short* Ob  = Vbf;            // BHS*64 bf16 = 14.2 MB < Vbf 15.7 MB
  float* ml  = (float*)wb;     // 4*BHS f32 = 1.77 MB < wb 3.54 MB

  prep_k<<<dim3(NBX_ + NBW_ + NBRX_), 256, 0, stream>>>(x, xb, w, wb, rpb, rpbX);
  qkv_mfma_k<<<dim3(QKV_WG_), 256, 0, stream>>>(xb, wb, Qbf, Ksw, Vbf);
  vtr_k<<<dim3(10, BN_ * HN_), 256, 0, stream>>>(Vbf, Vtsw);
  attn_k<<<dim3(1920), 256, 0, stream>>>(Qbf, Ksw, Vtsw, rpe, rpbX, Oa, Ob, ml);
  cmb_k<<<dim3(BHS_ * 8 / 256), 256, 0, stream>>>(Oa, Ob, ml, y);
}

// Round 21
// 134.253 us; speedup vs baseline: 1.1797x; 1.1797x over previous
//
#include <hip/hip_runtime.h>

// Problem constants
constexpr int BN_  = 16;                 // batch
constexpr int SN_  = 577;                // seq
constexpr int SP_  = 640;                // padded seq (multiple of 64)
constexpr int DN_  = 768;                // model dim
constexpr int HN_  = 12;                 // heads
constexpr int HD_  = 64;                 // head dim
constexpr int NB_  = 50;                 // rpe buckets
constexpr int MR_  = BN_ * SN_;          // 9232 rows of x
constexpr int MRP_ = 73 * 128;           // 9344 padded rows
constexpr int NQ_  = 3 * DN_;            // 2304 qkv cols
constexpr int BHS_ = BN_ * HN_ * SN_;    // 110784 (b,h,i) rows
constexpr int SHD_ = SN_ * HD_;          // 36928

constexpr int NBX_ = MRP_ * DN_ / 2048;  // 3504 blocks for x cvt
constexpr int NBW_ = NQ_ * DN_ / 2048;   // 864 blocks for w cvt
constexpr int NRPX_ = 5 * 4 * 2 * 10 * 4 * 64;   // 102400 dwords in rpbX
constexpr int NBRX_ = NRPX_ / 256;               // 400 blocks for rpbX

constexpr int QKV_WG_ = 18 * 73;         // 1314 qkv workgroups

typedef __attribute__((ext_vector_type(8))) short short8;
typedef __attribute__((ext_vector_type(4))) float f32x4;

__device__ __forceinline__ short f2bf(float f) {
  union { float f; unsigned u; } v; v.f = f;
  unsigned r = (v.u + 0x7fffu + ((v.u >> 16) & 1u)) >> 16;
  return (short)r;
}

// raw v_exp_f32: D = 2^S0 (handles -3e38 -> 0)
__device__ __forceinline__ float ex2(float x) {
  float r; asm("v_exp_f32 %0, %1" : "=v"(r) : "v"(x)); return r;
}

// v_cvt_pk_bf16_f32: dst = {lo16=bf16(a), hi16=bf16(b)}
__device__ __forceinline__ unsigned cvtpk(float a, float b) {
  unsigned r; asm("v_cvt_pk_bf16_f32 %0, %1, %2" : "=v"(r) : "v"(a), "v"(b));
  return r;
}

__device__ __forceinline__ float bf2f(unsigned short u) {
  union { unsigned u; float f; } v; v.u = ((unsigned)u) << 16; return v.f;
}

// async global->LDS, 16B per lane; LDS dest is wave-uniform base + lane*16
__device__ __forceinline__ void gload16(const void* g, void* l) {
  __builtin_amdgcn_global_load_lds(
      (const __attribute__((address_space(1))) unsigned int*)g,
      (__attribute__((address_space(3))) unsigned int*)l, 16, 0, 0);
}

// ---------------------------------------------------------------------------
// Kernel 0 (fused prep): x->bf16 (padded), w->bf16, rp_bucket->rpbX.
// rpbX layout (dwords): [qt][w][s][jt][nt][lane] so attn's bucket load per
// (s,nt) is ONE wave-coalesced dword load.
// ---------------------------------------------------------------------------
__launch_bounds__(256)
__global__ void prep_k(const float* __restrict__ x, short* __restrict__ xb,
                       const float* __restrict__ w, short* __restrict__ wb,
                       const int* __restrict__ rpb, unsigned* __restrict__ rpbX) {
  const int bid = blockIdx.x;
  const int t = threadIdx.x;
  if (bid < NBX_ + NBW_) {
    const float* src; short* dst; int n_src, i;
    if (bid < NBX_) { src = x; dst = xb; n_src = MR_ * DN_; i = (bid * 256 + t) * 8; }
    else { src = w; dst = wb; n_src = NQ_ * DN_; i = ((bid - NBX_) * 256 + t) * 8; }
    union { short8 v; short u[8]; } pk;
    if (i < n_src) {
      const float4 a = *(const float4*)(src + i);
      const float4 b = *(const float4*)(src + i + 4);
      pk.u[0] = f2bf(a.x); pk.u[1] = f2bf(a.y); pk.u[2] = f2bf(a.z); pk.u[3] = f2bf(a.w);
      pk.u[4] = f2bf(b.x); pk.u[5] = f2bf(b.y); pk.u[6] = f2bf(b.z); pk.u[7] = f2bf(b.w);
    } else {
#pragma unroll
      for (int j = 0; j < 8; ++j) pk.u[j] = 0;
    }
    *(short8*)(dst + i) = pk.v;
  } else {
    const int idx = (bid - NBX_ - NBW_) * 256 + t;   // dword index
    if (idx >= NRPX_) return;
    const int lane = idx & 63, chunk = idx >> 6;
    const int nt = chunk & 3;
    const int jt = (chunk >> 2) % 10;
    const int rest = chunk / 40;
    const int s  = rest & 1;
    const int w4 = (rest >> 1) & 3;
    const int qt = rest >> 3;
    const int g = lane >> 4, ln = lane & 15;
    int row = qt * 128 + w4 * 32 + s * 16 + ln;
    if (row > SN_ - 1) row = SN_ - 1;
    const int j0 = jt * 64 + nt * 16 + 4 * g;
    union { unsigned u; uchar4 c; } pk;
    pk.c.x = (j0     < SN_) ? (unsigned char)rpb[row * SN_ + j0    ] : 0;
    pk.c.y = (j0 + 1 < SN_) ? (unsigned char)rpb[row * SN_ + j0 + 1] : 0;
    pk.c.z = (j0 + 2 < SN_) ? (unsigned char)rpb[row * SN_ + j0 + 2] : 0;
    pk.c.w = (j0 + 3 < SN_) ? (unsigned char)rpb[row * SN_ + j0 + 3] : 0;
    rpbX[idx] = pk.u;
  }
}

// ---------------------------------------------------------------------------
// Kernel 1: qkv = x @ w^T in bf16 MFMA. 128x128 tile, BK=64, 4 waves (2x2).
// T4: 2-deep counted-vmcnt pipeline — prologue keeps 2 tiles in flight; per
// K-step wait s_waitcnt vmcnt(8) (oldest batch only), raw s_barrier, compute,
// barrier, issue tile k+2 into the just-read buffer. Last tile drains
// vmcnt(0). Pre-swizzled gload source; LDS-staged coalesced epilogue;
// bijective XCD swizzle.
// ---------------------------------------------------------------------------
__launch_bounds__(256)
__global__ void qkv_mfma_k(const short* __restrict__ xb, const short* __restrict__ wb,
                           short* __restrict__ Qbf, short* __restrict__ Ksw,
                           short* __restrict__ Vbf) {
  __shared__ short SB[32768];   // 64 KB: A buf0|A buf1|B buf0|B buf1; epilogue reuse
  const int t = threadIdx.x;
  const int w = t >> 6, lane = t & 63, g = lane >> 4, ln = lane & 15;
  const int wm = w >> 1, wn = w & 1;

  // bijective XCD swizzle: nwg=1314, 8 XCDs: q=164, r=2
  const int bid = blockIdx.x;
  const int xcd = bid & 7, li = bid >> 3;
  const int sid = (xcd < 2) ? xcd * 165 + li : 2 * 165 + (xcd - 2) * 164 + li;
  const int mi = sid / 18, ni = sid - mi * 18;
  const int m0 = mi * 128, n0 = ni * 128;

  const int rlo = lane >> 3;
  const int gu  = (lane & 7) ^ rlo;
  const short* ga[4]; const short* gb[4];
  int lOff[4];
#pragma unroll
  for (int q = 0; q < 4; ++q) {
    const int rl = w * 32 + q * 8 + rlo;
    ga[q] = xb + (size_t)(m0 + rl) * DN_ + gu * 8;
    gb[q] = wb + (size_t)(n0 + rl) * DN_ + gu * 8;
    lOff[q] = w * 2048 + q * 512;     // wave-uniform (shorts)
  }

  f32x4 acc[4][4];
#pragma unroll
  for (int mt = 0; mt < 4; ++mt)
#pragma unroll
    for (int nt = 0; nt < 4; ++nt) acc[mt][nt] = (f32x4){0.f, 0.f, 0.f, 0.f};

  // prologue: tile 0 -> buf0, tile 1 -> buf1 (16 loads in flight)
#pragma unroll
  for (int q = 0; q < 4; ++q) {
    gload16(ga[q], SB + lOff[q]);
    gload16(gb[q], SB + 16384 + lOff[q]);
  }
#pragma unroll
  for (int q = 0; q < 4; ++q) {
    gload16(ga[q] + 64, SB + 8192 + lOff[q]);
    gload16(gb[q] + 64, SB + 16384 + 8192 + lOff[q]);
  }

  int cur = 0;
  for (int k0 = 0; k0 < DN_; k0 += 64) {
    if (k0 + 64 < DN_) {
      asm volatile("s_waitcnt vmcnt(8)" ::: "memory");
    } else {
      asm volatile("s_waitcnt vmcnt(0)" ::: "memory");
    }
    __builtin_amdgcn_sched_barrier(0);
    __builtin_amdgcn_s_barrier();   // all waves' tile-k data visible
    __builtin_amdgcn_sched_barrier(0);

    const short* Ac = SB + cur * 8192;
    const short* Bc = SB + 16384 + cur * 8192;
#pragma unroll
    for (int kc = 0; kc < 2; ++kc) {
      short8 af[4], bf[4];
#pragma unroll
      for (int mt = 0; mt < 4; ++mt) {
        const int row = wm * 64 + mt * 16 + ln;
        const int u = (kc * 4 + g) ^ (row & 7);
        af[mt] = *(const short8*)&Ac[row * 64 + u * 8];
      }
#pragma unroll
      for (int nt = 0; nt < 4; ++nt) {
        const int row = wn * 64 + nt * 16 + ln;
        const int u = (kc * 4 + g) ^ (row & 7);
        bf[nt] = *(const short8*)&Bc[row * 64 + u * 8];
      }
#pragma unroll
      for (int mt = 0; mt < 4; ++mt)
#pragma unroll
        for (int nt = 0; nt < 4; ++nt)
          acc[mt][nt] = __builtin_amdgcn_mfma_f32_16x16x32_bf16(af[mt], bf[nt], acc[mt][nt], 0, 0, 0);
    }

    __builtin_amdgcn_s_barrier();   // all reads of buf[cur] done
    __builtin_amdgcn_sched_barrier(0);

    if (k0 + 128 < DN_) {  // issue tile k+2 into the just-read buffer
      const int nb = cur * 8192;
#pragma unroll
      for (int q = 0; q < 4; ++q) {
        gload16(ga[q] + k0 + 128, SB + nb + lOff[q]);
        gload16(gb[q] + k0 + 128, SB + 16384 + nb + lOff[q]);
      }
    }
    cur ^= 1;
  }

  // ---- epilogue: stage C tile (bf16) through LDS, coalesced 16B stores ----
  const int wbase = w * 4608;               // 64 rows x stride 72 per wave
  const int nw0  = n0 + wn * 64;
  const int secg = nw0 / DN_;               // uniform per wave
  const int cbw  = nw0 - secg * DN_;
  const float QSC = 0.18033688011112042f;   // log2(e) / 8
#pragma unroll
  for (int mt = 0; mt < 4; ++mt)
#pragma unroll
    for (int nt = 0; nt < 4; ++nt)
#pragma unroll
      for (int r = 0; r < 4; ++r) {
        float v = acc[mt][nt][r];
        if (secg == 0) v *= QSC;
        SB[wbase + (mt * 16 + 4 * g + r) * 72 + nt * 16 + ln] = f2bf(v);
      }
  const int gm = m0 + wm * 64 + lane;
  if (gm < MR_) {
    const int bb = gm / SN_;
    const int ss = gm - bb * SN_;
    const int pr = ss * DN_ + cbw;          // multiple of 64
    const int hh = pr / SHD_;
    const int ii = (pr - hh * SHD_) >> 6;
    const size_t ro = (size_t)(bb * HN_ + hh);
    const short* src = SB + wbase + lane * 72;
    if (secg == 0) {
      short* dst = Qbf + (ro * SN_ + ii) * 64;
#pragma unroll
      for (int u = 0; u < 8; ++u)
        *(short8*)(dst + u * 8) = *(const short8*)(src + u * 8);
    } else if (secg == 1) {
      short* dst = Ksw + (ro * SP_ + ii) * 64;
      const int sw = ii & 7;
#pragma unroll
      for (int u = 0; u < 8; ++u)
        *(short8*)(dst + (u ^ sw) * 8) = *(const short8*)(src + u * 8);
    } else {
      short* dst = Vbf + (ro * SP_ + ii) * 64;
#pragma unroll
      for (int u = 0; u < 8; ++u)
        *(short8*)(dst + u * 8) = *(const short8*)(src + u * 8);
    }
  }
}

// ---------------------------------------------------------------------------
// Kernel 2: transpose V per (bh): Vbf[j][d] -> Vtsw[d][pi(j)], bf16.
// pi permutes quads within each 32-col block: oq -> 2*(oq&3) + (oq>>2),
// so the attention PV custom slot map reads ONE contiguous b128 per frag.
// Then XOR-swizzle on 8-short units with (d&7). Pad cols j>=577 zeroed.
// ---------------------------------------------------------------------------
__launch_bounds__(256)
__global__ void vtr_k(const short* __restrict__ Vbf, short* __restrict__ Vtsw) {
  __shared__ short T[64][72];
  const int t = threadIdx.x;
  const int jt = blockIdx.x, bh = blockIdx.y;
  const int j0 = jt * 64;
  {
    const int r = t >> 2, c0 = (t & 3) * 16;
    const short* src = Vbf + ((size_t)bh * SP_ + j0 + r) * 64 + c0;
    *(short8*)&T[r][c0]     = *(const short8*)(src);
    *(short8*)&T[r][c0 + 8] = *(const short8*)(src + 8);
  }
  __syncthreads();
  const int d = t >> 2;
  short* dst = Vtsw + ((size_t)bh * 64 + d) * SP_;
  const int sw = (d & 7) << 3;
#pragma unroll
  for (int e = 0; e < 4; ++e) {
    const int jl = (t & 3) * 16 + e * 4;
    const int jg = j0 + jl;
    short4 v;
    v.x = (jg + 0 < SN_) ? T[jl + 0][d] : (short)0;
    v.y = (jg + 1 < SN_) ? T[jl + 1][d] : (short)0;
    v.z = (jg + 2 < SN_) ? T[jl + 2][d] : (short)0;
    v.w = (jg + 3 < SN_) ? T[jl + 3][d] : (short)0;
    const int oq = (jg >> 2) & 7;
    const int pq = ((oq & 3) << 1) | (oq >> 2);
    const int p  = (jg & ~31) | (pq << 2);
    *(short4*)&dst[p ^ sw] = v;
  }
}

// ---------------------------------------------------------------------------
// Kernel 3: MFMA flash attention (measured-best 61.2 µs config, R15 exact:
// reg-staged K/V, 2 barriers/jt, coalesced rpbX buckets, Rp/ctxs overlay,
// q-tile 128 (4 waves x 32 rows), permuted V single-b128 PV frags,
// swapped-QK in-reg softmax, exp2, bf16 ctx, cvtpk pack, setprio, defer-max,
// tail-only mask, XCD swizzle). Split-K (R19) reverted: prologue duplication
// + combine cost outweighed the TLP gain.
// ---------------------------------------------------------------------------
__launch_bounds__(256)
__global__ void attn_k(const short* __restrict__ Qbf, const short* __restrict__ Ksw,
                       const short* __restrict__ Vtsw, const float* __restrict__ rpe,
                       const unsigned* __restrict__ rpbX, float* __restrict__ y) {
  __shared__ short Kt[4096];                  // 8 KB
  __shared__ short Vt[4096];                  // 8 KB
  __shared__ unsigned short ctxs[4][32][53];  // 13.25 KB bf16; Rp overlays it
  short (*Rp)[64] = (short (*)[64])ctxs;      // [64][64] bf16, prologue only

  const int t = threadIdx.x;
  const int w = t >> 6, lane = t & 63, g = lane >> 4, ln = lane & 15;
  // XCD swizzle: all 5 q-tiles of one bh share an XCD
  const int wg = blockIdx.x;
  const int xcd = wg & 7, idx = wg >> 3;
  const int qt = idx % 5;
  const int bh = (idx / 5) * 8 + xcd;
  const int b = bh / HN_, h = bh - b * HN_;
  const int i0 = qt * 128;
  const size_t rb = (size_t)bh * SN_;
  const short* Kbh = Ksw + (size_t)bh * SP_ * 64;
  const short* Vbh = Vtsw + (size_t)bh * 64 * SP_;

  // staging maps
  const int tK = t * 8;                          // K/V: linear, 2x 16B
  const int vRow = t >> 3, vCol = (t & 7) * 8;   // V global rows

  // coalesced bucket-table base
  const unsigned* rpB = rpbX + qt * 20480 + w * 5120 + lane;

  // issue tile 0 K/V loads
  short8 kr0, kr1, vr0, vr1;
  kr0 = *(const short8*)(Kbh + tK);
  kr1 = *(const short8*)(Kbh + 2048 + tK);
  vr0 = *(const short8*)(Vbh + (size_t)vRow * SP_ + vCol);
  vr1 = *(const short8*)(Vbh + (size_t)(32 + vRow) * SP_ + vCol);

  // stage rpe^T -> Rp[c][d] (bf16), pad c>=50 with 0   (overlays ctxs)
  for (int e = t; e < 64 * 64; e += 256) {
    const int c = e >> 6, d = e & 63;
    Rp[c][d] = (c < NB_) ? f2bf(rpe[d * NB_ + c]) : (short)0;
  }

  // Q fragments, 2 sets: set s covers rows i0 + 32w + 16s + ln
  short8 qf[2][2];
#pragma unroll
  for (int s = 0; s < 2; ++s) {
    int row = i0 + 32 * w + 16 * s + ln; if (row > SN_ - 1) row = SN_ - 1;
    const short* qp = Qbf + (rb + row) * 64;
    qf[s][0] = *(const short8*)(qp + 8 * g);
    qf[s][1] = *(const short8*)(qp + 32 + 8 * g);
  }

  __syncthreads();  // B1: Rp visible

  // ctx tiles (both sets) into registers
  f32x4 accC[2][4];
#pragma unroll
  for (int s = 0; s < 2; ++s)
#pragma unroll
    for (int ct = 0; ct < 4; ++ct) accC[s][ct] = (f32x4){0.f, 0.f, 0.f, 0.f};
#pragma unroll
  for (int kc = 0; kc < 2; ++kc) {
#pragma unroll
    for (int ct = 0; ct < 4; ++ct) {
      const short8 rf = *(const short8*)&Rp[ct * 16 + ln][kc * 32 + 8 * g];
      accC[0][ct] = __builtin_amdgcn_mfma_f32_16x16x32_bf16(qf[0][kc], rf, accC[0][ct], 0, 0, 0);
      accC[1][ct] = __builtin_amdgcn_mfma_f32_16x16x32_bf16(qf[1][kc], rf, accC[1][ct], 0, 0, 0);
    }
  }
  __syncthreads();  // B2: ALL waves' Rp reads done -> ctxs overlay safe

  // write ctxs (bf16); wave-local region, read only by this wave
#pragma unroll
  for (int s = 0; s < 2; ++s)
#pragma unroll
    for (int ct = 0; ct < 4; ++ct) {
      const int c = ct * 16 + ln;
      if (c < 53) {
#pragma unroll
        for (int r = 0; r < 4; ++r)
          ctxs[w][16 * s + 4 * g + r][c] = (unsigned short)f2bf(accC[s][ct][r]);
      }
    }

  float m0s = -3e38f, m1s = -3e38f, l0s = 0.f, l1s = 0.f;
  f32x4 accO[2][4];
#pragma unroll
  for (int s = 0; s < 2; ++s)
#pragma unroll
    for (int dt = 0; dt < 4; ++dt) accO[s][dt] = (f32x4){0.f, 0.f, 0.f, 0.f};

  const int swv = (ln & 7) << 3;

  for (int jt = 0; jt < 10; ++jt) {
    __syncthreads();  // B_a: previous compute's LDS reads done
    *(short8*)&Kt[tK]        = kr0;
    *(short8*)&Kt[2048 + tK] = kr1;
    *(short8*)&Vt[tK]        = vr0;
    *(short8*)&Vt[2048 + tK] = vr1;
    __syncthreads();  // B_b: tiles visible

    // bucket loads for THIS tile: 8 wave-coalesced dwords (L2-resident)
    unsigned rpg[2][4];
#pragma unroll
    for (int s = 0; s < 2; ++s)
#pragma unroll
      for (int nt = 0; nt < 4; ++nt)
        rpg[s][nt] = rpB[s * 2560 + jt * 256 + nt * 64];

    if (jt < 9) {  // prefetch next K/V tile
      const int jn = jt * 64 + 64;
      kr0 = *(const short8*)(Kbh + (size_t)jn * 64 + tK);
      kr1 = *(const short8*)(Kbh + (size_t)jn * 64 + 2048 + tK);
      vr0 = *(const short8*)(Vbh + (size_t)vRow * SP_ + jn + vCol);
      vr1 = *(const short8*)(Vbh + (size_t)(32 + vRow) * SP_ + jn + vCol);
    }

    // QK^T both sets (K frags shared): accS[s][nt][r] = S_s[i=ln][j=nt*16+4g+r]
    f32x4 accS[2][4];
#pragma unroll
    for (int s = 0; s < 2; ++s)
#pragma unroll
      for (int nt = 0; nt < 4; ++nt) accS[s][nt] = (f32x4){0.f, 0.f, 0.f, 0.f};
    __builtin_amdgcn_s_setprio(1);
#pragma unroll
    for (int kc = 0; kc < 2; ++kc) {
      const int cb = (kc * 32 + 8 * g) ^ swv;
#pragma unroll
      for (int nt = 0; nt < 4; ++nt) {
        const short8 kf = *(const short8*)&Kt[(nt * 16 + ln) * 64 + cb];
        accS[0][nt] = __builtin_amdgcn_mfma_f32_16x16x32_bf16(kf, qf[0][kc], accS[0][nt], 0, 0, 0);
        accS[1][nt] = __builtin_amdgcn_mfma_f32_16x16x32_bf16(kf, qf[1][kc], accS[1][nt], 0, 0, 0);
      }
    }
    __builtin_amdgcn_s_setprio(0);

    // per set: bias + softmax + pack
    short8 pf[2][2];
#pragma unroll
    for (int s = 0; s < 2; ++s) {
      const unsigned short* cbase = &ctxs[w][16 * s + ln][0];
      float pv[4][4];
#pragma unroll
      for (int nt = 0; nt < 4; ++nt) {
        union { unsigned u; uchar4 c; } bk; bk.u = rpg[s][nt];
        pv[nt][0] = accS[s][nt][0] + bf2f(cbase[bk.c.x]);
        pv[nt][1] = accS[s][nt][1] + bf2f(cbase[bk.c.y]);
        pv[nt][2] = accS[s][nt][2] + bf2f(cbase[bk.c.z]);
        pv[nt][3] = accS[s][nt][3] + bf2f(cbase[bk.c.w]);
      }
      if (jt == 9) {  // tail: REPLACE invalid-j entries (poison-proof)
#pragma unroll
        for (int nt = 0; nt < 4; ++nt) {
          const int jb = jt * 64 + nt * 16 + 4 * g;
#pragma unroll
          for (int r = 0; r < 4; ++r)
            if (jb + r >= SN_) pv[nt][r] = -3e38f;
        }
      }

      float& m = (s == 0) ? m0s : m1s;
      float& l = (s == 0) ? l0s : l1s;

      float mq[4];
#pragma unroll
      for (int nt = 0; nt < 4; ++nt)
        mq[nt] = fmaxf(fmaxf(pv[nt][0], pv[nt][1]), fmaxf(pv[nt][2], pv[nt][3]));
      float mx = fmaxf(fmaxf(mq[0], mq[1]), fmaxf(mq[2], mq[3]));
      mx = fmaxf(mx, __shfl_xor(mx, 16));
      mx = fmaxf(mx, __shfl_xor(mx, 32));

      if (__any(mx > m + 8.f)) {
        const float mnew = fmaxf(m, mx);
        const float sc = ex2(m - mnew);
        float scr[4];
#pragma unroll
        for (int r = 0; r < 4; ++r) scr[r] = __shfl(sc, 4 * g + r);
#pragma unroll
        for (int dt = 0; dt < 4; ++dt)
#pragma unroll
          for (int r = 0; r < 4; ++r) accO[s][dt][r] *= scr[r];
        l *= sc;
        m = mnew;
      }

#pragma unroll
      for (int nt = 0; nt < 4; ++nt)
#pragma unroll
        for (int r = 0; r < 4; ++r)
          pv[nt][r] = ex2(pv[nt][r] - m);
      float sq[4];
#pragma unroll
      for (int nt = 0; nt < 4; ++nt)
        sq[nt] = (pv[nt][0] + pv[nt][1]) + (pv[nt][2] + pv[nt][3]);
      float sum = (sq[0] + sq[1]) + (sq[2] + sq[3]);
      sum += __shfl_xor(sum, 16);
      sum += __shfl_xor(sum, 32);
      l += sum;

#pragma unroll
      for (int kc = 0; kc < 2; ++kc) {
        union { short8 v; unsigned wd[4]; } pk;
        pk.wd[0] = cvtpk(pv[2 * kc][0],     pv[2 * kc][1]);
        pk.wd[1] = cvtpk(pv[2 * kc][2],     pv[2 * kc][3]);
        pk.wd[2] = cvtpk(pv[2 * kc + 1][0], pv[2 * kc + 1][1]);
        pk.wd[3] = cvtpk(pv[2 * kc + 1][2], pv[2 * kc + 1][3]);
        pf[s][kc] = pk.v;
      }
    }

    // PV both sets (V frags shared, single b128 each thanks to permuted V)
    __builtin_amdgcn_s_setprio(1);
#pragma unroll
    for (int kc = 0; kc < 2; ++kc) {
      const int cb = (kc * 32 + 8 * g) ^ swv;
#pragma unroll
      for (int dt = 0; dt < 4; ++dt) {
        const short8 vf = *(const short8*)&Vt[(dt * 16 + ln) * 64 + cb];
        accO[0][dt] = __builtin_amdgcn_mfma_f32_16x16x32_bf16(pf[0][kc], vf, accO[0][dt], 0, 0, 0);
        accO[1][dt] = __builtin_amdgcn_mfma_f32_16x16x32_bf16(pf[1][kc], vf, accO[1][dt], 0, 0, 0);
      }
    }
    __builtin_amdgcn_s_setprio(0);
  }

  // epilogue: y[b, i, h*64 + d] = O / l
#pragma unroll
  for (int s = 0; s < 2; ++s) {
    const float lv = (s == 0) ? l0s : l1s;
    float linv[4];
#pragma unroll
    for (int r = 0; r < 4; ++r) linv[r] = 1.f / __shfl(lv, 4 * g + r);
#pragma unroll
    for (int r = 0; r < 4; ++r) {
      const int i = i0 + 32 * w + 16 * s + 4 * g + r;
      if (i >= SN_) continue;
      float* yp = y + ((size_t)b * SN_ + i) * DN_ + h * HD_ + ln;
#pragma unroll
      for (int dt = 0; dt < 4; ++dt) yp[dt * 16] = accO[s][dt][r] * linv[r];
    }
  }
}

// ---------------------------------------------------------------------------
extern "C" void kernel_launch(void* const* d_in, const int* in_sizes, int n_in,
                              void* d_out, int out_size, void* d_ws, size_t ws_size,
                              hipStream_t stream) {
  const float* x   = (const float*)d_in[0];
  const float* w   = (const float*)d_in[1];
  const float* rpe = (const float*)d_in[2];
  const int*   rpb = (const int*)d_in[3];
  float* y = (float*)d_out;

  short* xb   = (short*)d_ws;                      // 9344*768
  short* wb   = xb + (size_t)MRP_ * DN_;           // 2304*768
  short* Qbf  = wb + (size_t)NQ_ * DN_;            // 110784*64
  short* Ksw  = Qbf + (size_t)BHS_ * HD_;          // 192*640*64
  short* Vbf  = Ksw + (size_t)BN_ * HN_ * SP_ * 64;
  short* Vtsw = Vbf + (size_t)BN_ * HN_ * SP_ * 64;
  unsigned* rpbX = (unsigned*)(Vtsw + (size_t)BN_ * HN_ * 64 * SP_);  // 400 KB

  prep_k<<<dim3(NBX_ + NBW_ + NBRX_), 256, 0, stream>>>(x, xb, w, wb, rpb, rpbX);
  qkv_mfma_k<<<dim3(QKV_WG_), 256, 0, stream>>>(xb, wb, Qbf, Ksw, Vbf);
  vtr_k<<<dim3(10, BN_ * HN_), 256, 0, stream>>>(Vbf, Vtsw);
  attn_k<<<dim3(960), 256, 0, stream>>>(Qbf, Ksw, Vtsw, rpe, rpbX, y);
}